// Round 8
// baseline (178.702 us; speedup 1.0000x reference)
//
#include <hip/hip_runtime.h>
#include <hip/hip_bf16.h>
#include <math.h>

#define NN 1024

typedef __attribute__((ext_vector_type(8))) short bf16x8;
typedef __attribute__((ext_vector_type(4))) float f32x4;

__device__ __forceinline__ float wave_sum(float v) {
#pragma unroll
  for (int off = 32; off > 0; off >>= 1) v += __shfl_down(v, off);
  return v;
}
__device__ __forceinline__ short f2bf(float x) {
  __hip_bfloat16 b = __float2bfloat16(x);
  return *(short*)&b;
}

#define SH_C0 0.28209479177387814f
#define SH_C1 0.4886025119029199f
#define SH_S15 1.0925484305920792f
#define SH_S5 0.6307831305050401f

// ---------------------------------------------------------------------------
// K1: fused independent staging (block ranges):
//   [0,8)       weights fp32->bf16 (q,k,v0,v1,v2,o0,o1,o2) [o][i] layout
//   [8,1160)    x_emb -> bf16
//   [1160,1448) fT[c][k=m*1024+i] bf16 (LDS transpose)
//   [1448,2472) Wsh[j][k=m*1024+i] bf16 (sh*idg*valid folded)
//   [2472,3496) row stats + fused rowmean -> rowm_bf
__global__ __launch_bounds__(256) void htr_geom(
    const float* __restrict__ qw, const float* __restrict__ kw,
    const float* __restrict__ vw, const float* __restrict__ ow,
    const float* __restrict__ x_emb, const float* __restrict__ pos,
    const int* __restrict__ batch, short* __restrict__ wbf,
    short* __restrict__ x_bf, short* __restrict__ fT,
    short* __restrict__ Wsh, short* __restrict__ rowm_bf) {
  const int b = blockIdx.x;
  const int tid = threadIdx.x;
  __shared__ short tile[128][34];
  __shared__ float red[4][9];
  __shared__ float sm[9];

  if (b < 8) {
    const float* src;
    if (b == 0) src = qw;
    else if (b == 1) src = kw;
    else if (b < 5) src = vw + (b - 2) * 16384;
    else src = ow + (b - 5) * 16384;
    short* dst = wbf + b * 16384;
    for (int idx = tid; idx < 16384; idx += 256) dst[idx] = f2bf(src[idx]);
  } else if (b < 1160) {
    int base = (b - 8) * 1024 + tid * 4;
    float4 v = *(const float4*)(x_emb + base);
    *(short4*)(x_bf + base) = make_short4(f2bf(v.x), f2bf(v.y), f2bf(v.z), f2bf(v.w));
  } else if (b < 1448) {
    const int sub = b - 1160;
    const int i0 = (sub & 31) * 32;
    const int m = sub >> 5;
#pragma unroll
    for (int it = 0; it < 16; ++it) {
      int e = tid + it * 256;
      int r = e >> 7, c = e & 127;
      tile[c][r] = f2bf(x_emb[((i0 + r) * 9 + m) * 128 + c]);
    }
    __syncthreads();
#pragma unroll
    for (int it = 0; it < 8; ++it) {
      int idx = tid + it * 256;
      int c = idx >> 4, ii2 = idx & 15;
      *(short2*)(fT + c * 9216 + m * 1024 + i0 + ii2 * 2) =
          make_short2(tile[c][ii2 * 2], tile[c][ii2 * 2 + 1]);
    }
  } else if (b < 2472) {
    const int j = b - 1448;
    const float pjx = pos[j * 3 + 0], pjy = pos[j * 3 + 1], pjz = pos[j * 3 + 2];
    const int bj = batch[j];
    short* wrow = Wsh + j * 9216;
    for (int i = tid; i < 1024; i += 256) {
      float dx = pos[i * 3 + 0] - pjx;
      float dy = pos[i * 3 + 1] - pjy;
      float dz = pos[i * 3 + 2] - pjz;
      bool ok = (i != j) && (batch[i] == bj);
      float okf = ok ? 1.f : 0.f;
      float d2 = dx * dx + dy * dy + dz * dz;
      float inv = okf / fmaxf(sqrtf(d2), 1e-8f);
      float x = dx * inv, y = dy * inv, z = dz * inv;
      wrow[0 * 1024 + i] = f2bf(SH_C0 * okf);
      wrow[1 * 1024 + i] = f2bf((SH_C1 * (1.f / 3.f)) * x);
      wrow[2 * 1024 + i] = f2bf((SH_C1 * (1.f / 3.f)) * y);
      wrow[3 * 1024 + i] = f2bf((SH_C1 * (1.f / 3.f)) * z);
      wrow[4 * 1024 + i] = f2bf((SH_S15 * 0.2f) * x * z);
      wrow[5 * 1024 + i] = f2bf((SH_S15 * 0.2f) * x * y);
      wrow[6 * 1024 + i] = f2bf((SH_S5 * 0.2f) * (y * y - 0.5f * (x * x + z * z)));
      wrow[7 * 1024 + i] = f2bf((SH_S15 * 0.2f) * y * z);
      wrow[8 * 1024 + i] = f2bf((0.5f * SH_S15 * 0.2f) * (z * z - x * x));
    }
  } else {
    const int i = b - 2472;
    const float px = pos[i * 3 + 0], py = pos[i * 3 + 1], pz = pos[i * 3 + 2];
    const int bi = batch[i];
    float s[9];
#pragma unroll
    for (int m = 0; m < 9; ++m) s[m] = 0.f;
    for (int j = tid; j < NN; j += 256) {
      if (j == i) continue;
      if (batch[j] != bi) continue;
      float dx = px - pos[j * 3 + 0];
      float dy = py - pos[j * 3 + 1];
      float dz = pz - pos[j * 3 + 2];
      float d2 = dx * dx + dy * dy + dz * dz;
      float inv = 1.0f / fmaxf(sqrtf(d2), 1e-8f);
      float x = dx * inv, y = dy * inv, z = dz * inv;
      s[0] += 1.0f;
      s[1] += x; s[2] += y; s[3] += z;
      s[4] += x * z; s[5] += x * y;
      s[6] += y * y - 0.5f * (x * x + z * z);
      s[7] += y * z;
      s[8] += z * z - x * x;
    }
    const int wave = tid >> 6, lane = tid & 63;
#pragma unroll
    for (int m = 0; m < 9; ++m) {
      float v = wave_sum(s[m]);
      if (lane == 0) red[wave][m] = v;
    }
    __syncthreads();
    if (tid < 9) {
      float v = red[0][tid] + red[1][tid] + red[2][tid] + red[3][tid];
      float scl = SH_S15 * 0.2f;
      if (tid == 0) scl = SH_C0;
      else if (tid < 4) scl = SH_C1 * (1.f / 3.f);
      else if (tid == 6) scl = SH_S5 * 0.2f;
      else if (tid == 8) scl = 0.5f * SH_S15 * 0.2f;
      sm[tid] = v * scl * (1.0f / 1024.0f);
    }
    __syncthreads();
    if (tid < 128) {
      float acc = 0.f;
#pragma unroll
      for (int m = 0; m < 9; ++m)
        acc = fmaf(sm[m], x_emb[(i * 9 + m) * 128 + tid], acc);
      rowm_bf[i * 128 + tid] = f2bf(acc);
    }
  }
}

// ---------------------------------------------------------------------------
// K2: colmean partial GEMM. CMS=32 k-splits -> 2048 waves = 2/SIMD for
// latency hiding. Chunk K = 288 = 9 steps of 32.
#define CMS 32
__global__ __launch_bounds__(64) void htr_colmean_mfma(
    const short* __restrict__ Wsh, const short* __restrict__ fT,
    float* __restrict__ part) {
  const int jbase = blockIdx.x * 16;
  const int ks = blockIdx.y;
  const int lane = threadIdx.x;
  const int q = lane >> 4, l15 = lane & 15;
  const short* ap = Wsh + (jbase + l15) * 9216 + ks * 288 + q * 8;
  const short* bp = fT + l15 * 9216 + ks * 288 + q * 8;
  f32x4 acc[8];
#pragma unroll
  for (int t = 0; t < 8; ++t) acc[t] = (f32x4){0.f, 0.f, 0.f, 0.f};
  bf16x8 a = *(const bf16x8*)ap;
  bf16x8 b[8];
#pragma unroll
  for (int t = 0; t < 8; ++t) b[t] = *(const bf16x8*)(bp + t * 147456);
  for (int s = 1; s < 9; ++s) {
    const int off = s * 32;
    bf16x8 an = *(const bf16x8*)(ap + off);
    bf16x8 bn[8];
#pragma unroll
    for (int t = 0; t < 8; ++t) bn[t] = *(const bf16x8*)(bp + t * 147456 + off);
#pragma unroll
    for (int t = 0; t < 8; ++t)
      acc[t] = __builtin_amdgcn_mfma_f32_16x16x32_bf16(a, b[t], acc[t], 0, 0, 0);
    a = an;
#pragma unroll
    for (int t = 0; t < 8; ++t) b[t] = bn[t];
  }
#pragma unroll
  for (int t = 0; t < 8; ++t)
    acc[t] = __builtin_amdgcn_mfma_f32_16x16x32_bf16(a, b[t], acc[t], 0, 0, 0);
#pragma unroll
  for (int t = 0; t < 8; ++t)
#pragma unroll
    for (int r = 0; r < 4; ++r)
      part[(ks * 1024 + jbase + q * 4 + r) * 128 + t * 16 + l15] = acc[t][r];
}

// ---------------------------------------------------------------------------
// K3: fused projections (1-wave MFMA), grid (64, 11):
//   y==0: q = rowm@q_w^T+q_b, *0.25 -> qb16 [h][i][32] bf16 (upper 16 = 0)
//   y==1: k = colm@k_w^T+k_b        -> khbT [h][j][32] bf16 (upper 16 = 0)
//         (colm inline: fp32 sum of CMS part slices)
//   y>=2: v[m] = x@v_w[l]^T (+b0)   -> vbT  [h][n][k=j] bf16
__global__ __launch_bounds__(64) void htr_proj(
    const short* __restrict__ rowm_bf, const float* __restrict__ part,
    const short* __restrict__ x_bf, const short* __restrict__ wbf,
    const float* __restrict__ q_b, const float* __restrict__ k_b,
    const float* __restrict__ v_b0, short* __restrict__ qb16,
    short* __restrict__ khbT, short* __restrict__ vbT) {
  const int ibase = blockIdx.x * 16;
  const int y = blockIdx.y;
  const int lane = threadIdx.x;
  const int q = lane >> 4, l15 = lane & 15;

  bf16x8 a[4];
  const short* bp;
  if (y == 0) {
    const short* ap = rowm_bf + (ibase + l15) * 128 + q * 8;
#pragma unroll
    for (int ks = 0; ks < 4; ++ks) a[ks] = *(const bf16x8*)(ap + ks * 32);
    bp = wbf + l15 * 128 + q * 8;
  } else if (y == 1) {
    const float* pp = part + (size_t)(ibase + l15) * 128;
#pragma unroll
    for (int ks = 0; ks < 4; ++ks) {
      float s0 = 0.f, s1 = 0.f, s2 = 0.f, s3 = 0.f;
      float s4 = 0.f, s5 = 0.f, s6 = 0.f, s7 = 0.f;
      for (int s = 0; s < CMS; ++s) {
        const float* ps = pp + s * 131072 + ks * 32 + q * 8;
        float4 u0 = *(const float4*)(ps);
        float4 u1 = *(const float4*)(ps + 4);
        s0 += u0.x; s1 += u0.y; s2 += u0.z; s3 += u0.w;
        s4 += u1.x; s5 += u1.y; s6 += u1.z; s7 += u1.w;
      }
      const float sc = 1.0f / 1024.0f;
      bf16x8 av;
      av[0] = f2bf(s0 * sc); av[1] = f2bf(s1 * sc);
      av[2] = f2bf(s2 * sc); av[3] = f2bf(s3 * sc);
      av[4] = f2bf(s4 * sc); av[5] = f2bf(s5 * sc);
      av[6] = f2bf(s6 * sc); av[7] = f2bf(s7 * sc);
      a[ks] = av;
    }
    bp = wbf + 16384 + l15 * 128 + q * 8;
  } else {
    const int m = y - 2;
    const int l = (m == 0) ? 0 : ((m < 4) ? 1 : 2);
    const short* ap = x_bf + ((ibase + l15) * 9 + m) * 128 + q * 8;
#pragma unroll
    for (int ks = 0; ks < 4; ++ks) a[ks] = *(const bf16x8*)(ap + ks * 32);
    bp = wbf + (2 + l) * 16384 + l15 * 128 + q * 8;
  }

  f32x4 acc[8];
#pragma unroll
  for (int t = 0; t < 8; ++t) {
    acc[t] = (f32x4){0.f, 0.f, 0.f, 0.f};
    const short* bt = bp + t * 2048;
#pragma unroll
    for (int ks = 0; ks < 4; ++ks) {
      bf16x8 b = *(const bf16x8*)(bt + ks * 32);
      acc[t] = __builtin_amdgcn_mfma_f32_16x16x32_bf16(a[ks], b, acc[t], 0, 0, 0);
    }
  }

  if (y == 0) {
#pragma unroll
    for (int t = 0; t < 8; ++t) {       // t = head h, l15 = d
      float bo = q_b[t * 16 + l15];
#pragma unroll
      for (int r = 0; r < 4; ++r) {
        int i = ibase + q * 4 + r;
        qb16[(t * 1024 + i) * 32 + l15] = f2bf((acc[t][r] + bo) * 0.25f);
        qb16[(t * 1024 + i) * 32 + 16 + l15] = 0;
      }
    }
  } else if (y == 1) {
#pragma unroll
    for (int t = 0; t < 8; ++t) {       // t = head h, l15 = d
      float bo = k_b[t * 16 + l15];
#pragma unroll
      for (int r = 0; r < 4; ++r) {
        int j = ibase + q * 4 + r;
        khbT[(t * 1024 + j) * 32 + l15] = f2bf(acc[t][r] + bo);
        khbT[(t * 1024 + j) * 32 + 16 + l15] = 0;
      }
    }
  } else {
    const int m = y - 2;
#pragma unroll
    for (int t = 0; t < 8; ++t) {
      float bias = (m == 0) ? v_b0[t * 16 + l15] : 0.f;
#pragma unroll
      for (int r = 0; r < 4; ++r)
        vbT[(t * 144 + m * 16 + l15) * 1024 + ibase + q * 4 + r] =
            f2bf(acc[t][r] + bias);
    }
  }
}

// ---------------------------------------------------------------------------
// K4: flash attention: scores (MFMA, K=32 zero-padded) + masked softmax +
// PV (MFMA, P in LDS as B operand via the O^T trick). Grid (64 itile, 8 h),
// 256 thr = 4 waves (2 waves/SIMD). Wave w owns j-chunk w*256..w*256+255 for
// scores; PV splits n-tiles t = w, w+4, ... across waves.
#define PPITCH 1040
__global__ __launch_bounds__(256) void htr_flash(
    const short* __restrict__ qb16,  // [h][i][32] bf16 (0.25 folded, pad 0)
    const short* __restrict__ khbT,  // [h][j][32] bf16 (pad 0)
    const short* __restrict__ vbT,   // [h][n][k=j] bf16
    const int* __restrict__ batch,
    short* __restrict__ obuf_bf) {   // [i][m][128] bf16
  const int ibase = blockIdx.x * 16;
  const int h = blockIdx.y;
  const int tid = threadIdx.x;
  const int w = tid >> 6;
  const int lane = tid & 63;
  const int q = lane >> 4, l15 = lane & 15;
  __shared__ short P[16][PPITCH];       // 33.3 KB
  __shared__ int bsh[1024];
  __shared__ float redM[4][16], redS[4][16];

  for (int idx = tid; idx < 1024; idx += 256) bsh[idx] = batch[idx];
  __syncthreads();
  int bi[4];
#pragma unroll
  for (int r = 0; r < 4; ++r) bi[r] = bsh[ibase + q * 4 + r];

  // ---- scores for j in [w*256, w*256+256): 16 MFMAs ----
  bf16x8 aq = *(const bf16x8*)(qb16 + (h * 1024 + ibase + l15) * 32 + q * 8);
  f32x4 sc[16];
#pragma unroll
  for (int jt = 0; jt < 16; ++jt) {
    int jb = w * 256 + jt * 16;
    bf16x8 bk = *(const bf16x8*)(khbT + (h * 1024 + jb + l15) * 32 + q * 8);
    sc[jt] = __builtin_amdgcn_mfma_f32_16x16x32_bf16(
        aq, bk, (f32x4){0.f, 0.f, 0.f, 0.f}, 0, 0, 0);
    int bj = bsh[jb + l15];
#pragma unroll
    for (int r = 0; r < 4; ++r)
      if (bj != bi[r]) sc[jt][r] = -INFINITY;
  }
  // ---- row max (over this wave's 256 j), then cross-wave ----
  float mx[4];
#pragma unroll
  for (int r = 0; r < 4; ++r) {
    float m = sc[0][r];
#pragma unroll
    for (int jt = 1; jt < 16; ++jt) m = fmaxf(m, sc[jt][r]);
#pragma unroll
    for (int off = 1; off < 16; off <<= 1) m = fmaxf(m, __shfl_xor(m, off));
    mx[r] = m;
  }
  if (l15 == 0) {
#pragma unroll
    for (int r = 0; r < 4; ++r) redM[w][q * 4 + r] = mx[r];
  }
  __syncthreads();
  float M[4];
#pragma unroll
  for (int r = 0; r < 4; ++r) {
    int row = q * 4 + r;
    M[r] = fmaxf(fmaxf(redM[0][row], redM[1][row]),
                 fmaxf(redM[2][row], redM[3][row]));
  }
  // ---- exp + row sum ----
  float sm[4] = {0.f, 0.f, 0.f, 0.f};
#pragma unroll
  for (int jt = 0; jt < 16; ++jt) {
#pragma unroll
    for (int r = 0; r < 4; ++r) {
      float e = __expf(sc[jt][r] - M[r]);
      sc[jt][r] = e;
      sm[r] += e;
    }
  }
#pragma unroll
  for (int r = 0; r < 4; ++r) {
#pragma unroll
    for (int off = 1; off < 16; off <<= 1) sm[r] += __shfl_xor(sm[r], off);
  }
  if (l15 == 0) {
#pragma unroll
    for (int r = 0; r < 4; ++r) redS[w][q * 4 + r] = sm[r];
  }
  __syncthreads();
  float inv[4];
#pragma unroll
  for (int r = 0; r < 4; ++r) {
    int row = q * 4 + r;
    inv[r] = 1.0f / (redS[0][row] + redS[1][row] + redS[2][row] + redS[3][row]);
  }
  // ---- write P (bf16) to LDS, rows = i, cols = j ----
#pragma unroll
  for (int jt = 0; jt < 16; ++jt) {
    int col = w * 256 + jt * 16 + l15;
#pragma unroll
    for (int r = 0; r < 4; ++r)
      P[q * 4 + r][col] = f2bf(sc[jt][r] * inv[r]);
  }
  __syncthreads();
  // ---- PV: O^T[n][i] = sum_j V^T[n][j] * P^T[j][i] ----
  // A = vbT (lane l15 = n-row, k=j contiguous); B = P (lane l15 = i, k=j).
  for (int t = w; t < 9; t += 4) {
    f32x4 o = (f32x4){0.f, 0.f, 0.f, 0.f};
    const short* apv = vbT + (h * 144 + t * 16 + l15) * 1024 + q * 8;
#pragma unroll
    for (int kc = 0; kc < 32; ++kc) {
      bf16x8 av = *(const bf16x8*)(apv + kc * 32);
      bf16x8 bv = *(const bf16x8*)(&P[l15][kc * 32 + q * 8]);
      o = __builtin_amdgcn_mfma_f32_16x16x32_bf16(av, bv, o, 0, 0, 0);
    }
#pragma unroll
    for (int r = 0; r < 4; ++r)   // C: col=l15=i, row=q*4+r=d within tile t=m
      obuf_bf[((ibase + l15) * 9 + t) * 128 + h * 16 + q * 4 + r] =
          f2bf(o[r]);
  }
}

// ---------------------------------------------------------------------------
// K5: out-projection + residual + LayerNorm (fused MFMA epilogue).
__global__ __launch_bounds__(64) void htr_outln_mfma(
    const short* __restrict__ obuf_bf, const float* __restrict__ x_emb,
    const short* __restrict__ wbf, const float* __restrict__ ln_g,
    const float* __restrict__ ln_b, float* __restrict__ out) {
  const int ibase = blockIdx.x * 16;
  const int m = blockIdx.y;
  const int l = (m == 0) ? 0 : ((m < 4) ? 1 : 2);
  const int lane = threadIdx.x;
  const int q = lane >> 4, l15 = lane & 15;
  const short* ap = obuf_bf + ((ibase + l15) * 9 + m) * 128 + q * 8;
  const short* bp = wbf + (5 + l) * 16384 + l15 * 128 + q * 8;
  bf16x8 a[4];
#pragma unroll
  for (int ks = 0; ks < 4; ++ks) a[ks] = *(const bf16x8*)(ap + ks * 32);
  f32x4 acc[8];
#pragma unroll
  for (int t = 0; t < 8; ++t) {
    acc[t] = (f32x4){0.f, 0.f, 0.f, 0.f};
    const short* bt = bp + t * 2048;
#pragma unroll
    for (int ks = 0; ks < 4; ++ks) {
      bf16x8 b = *(const bf16x8*)(bt + ks * 32);
      acc[t] = __builtin_amdgcn_mfma_f32_16x16x32_bf16(a[ks], b, acc[t], 0, 0, 0);
    }
  }
  float g[8], bb[8];
#pragma unroll
  for (int t = 0; t < 8; ++t) {
    g[t] = ln_g[l * 128 + t * 16 + l15];
    bb[t] = ln_b[l * 128 + t * 16 + l15];
  }
#pragma unroll
  for (int r = 0; r < 4; ++r) {
    const int i = ibase + q * 4 + r;
    const float* xr = x_emb + (i * 9 + m) * 128;
    float v[8];
    float sv = 0.f, sq = 0.f;
#pragma unroll
    for (int t = 0; t < 8; ++t) {
      v[t] = acc[t][r] + xr[t * 16 + l15];
      sv += v[t];
      sq += v[t] * v[t];
    }
#pragma unroll
    for (int off = 1; off < 16; off <<= 1) {
      sv += __shfl_xor(sv, off);
      sq += __shfl_xor(sq, off);
    }
    float mu = sv * (1.f / 128.f);
    float var = sq * (1.f / 128.f) - mu * mu;
    float rs = rsqrtf(var + 1e-5f);
    float* orow = out + (i * 9 + m) * 128;
#pragma unroll
    for (int t = 0; t < 8; ++t)
      orow[t * 16 + l15] = (v[t] - mu) * rs * g[t] + bb[t];
  }
}

// ---------------------------------------------------------------------------
extern "C" void kernel_launch(void* const* d_in, const int* in_sizes, int n_in,
                              void* d_out, int out_size, void* d_ws, size_t ws_size,
                              hipStream_t stream) {
  (void)in_sizes; (void)n_in; (void)out_size; (void)ws_size;
  const float* x_emb = (const float*)d_in[0];
  const float* pos   = (const float*)d_in[1];
  const float* q_w   = (const float*)d_in[2];
  const float* q_b   = (const float*)d_in[3];
  const float* k_w   = (const float*)d_in[4];
  const float* k_b   = (const float*)d_in[5];
  const float* v_w   = (const float*)d_in[6];
  const float* v_b0  = (const float*)d_in[7];
  const float* out_w = (const float*)d_in[8];
  const float* ln_g  = (const float*)d_in[9];
  const float* ln_b  = (const float*)d_in[10];
  const int*   batch = (const int*)d_in[11];
  float* out = (float*)d_out;

  // workspace (float-slot offsets). part (CMS=32 -> 4,194,304 f) aliases the
  // former attn region exactly; dead after proj.
  float* ws = (float*)d_ws;
  short* rowm_bf = (short*)(ws + 0);         //   131,072 bf16
  short* qb16    = (short*)(ws + 65536);     //   262,144 bf16 [h][i][32]
  short* khbT    = (short*)(ws + 196608);    //   262,144 bf16 [h][j][32]
  short* wbf     = (short*)(ws + 327680);    //   131,072 bf16 (8 mats)
  short* x_bf    = (short*)(ws + 393216);    // 1,179,648 bf16
  short* vbT     = (short*)(ws + 983040);    // 1,179,648 bf16 [h][n][k]
  short* obuf_bf = (short*)(ws + 1572864);   // 1,179,648 bf16
  float* part    = ws + 2162688;             // 4,194,304 f
  short* Wsh     = (short*)(ws + 6356992);   // 9,437,184 bf16
  short* fT      = (short*)(ws + 11075584);  // 1,179,648 bf16

  htr_geom<<<3496, 256, 0, stream>>>(q_w, k_w, v_w, out_w, x_emb, pos, batch,
                                     wbf, x_bf, fT, Wsh, rowm_bf);
  htr_colmean_mfma<<<dim3(64, CMS), 64, 0, stream>>>(Wsh, fT, part);
  htr_proj<<<dim3(64, 11), 64, 0, stream>>>(rowm_bf, part, x_bf, wbf, q_b, k_b,
                                            v_b0, qb16, khbT, vbT);
  htr_flash<<<dim3(64, 8), 256, 0, stream>>>(qb16, khbT, vbT, batch, obuf_bf);
  htr_outln_mfma<<<dim3(64, 9), 64, 0, stream>>>(obuf_bf, x_emb, wbf, ln_g,
                                                 ln_b, out);
}